// Round 3
// baseline (2270.155 us; speedup 1.0000x reference)
//
#include <hip/hip_runtime.h>

#define NSTEP 10

// ---------------------------------------------------------------------------
// Prep: transpose W1 [256][250] -> W1T [250][256], W2 [128][256] -> W2T [256][128]
// ---------------------------------------------------------------------------
extern "C" __global__ void __launch_bounds__(256) snn_prep(
    const float* __restrict__ W1, const float* __restrict__ W2,
    float* __restrict__ W1T, float* __restrict__ W2T)
{
    int i0 = blockIdx.x * 256 + threadIdx.x;
    int stride = gridDim.x * 256;
    for (int idx = i0; idx < 250 * 256; idx += stride) {
        int k = idx >> 8;
        int n = idx & 255;
        W1T[idx] = W1[n * 250 + k];
    }
    for (int idx = i0; idx < 256 * 128; idx += stride) {
        int k = idx >> 7;
        int j = idx & 127;
        W2T[idx] = W2[j * 256 + k];
    }
}

// ---------------------------------------------------------------------------
// Main fused SNN kernel. 32 samples/block, 256 threads, 10 steps fused.
//
// Design (R3): sized so ~120 live floats fit the 128-VGPR allocation the
// backend insists on (R1/R2 evidence: 64-sample blocks need >=160 live ->
// unavoidable spills, 68 MB/dispatch scratch writes).
//
// Thread maps:
//   L1/prologue: nt=t&15 (16 neurons n0=nt*16), st=t>>4 (2 samples s0a=st*2)
//   L2 GEMM:     jt=t&31 (4 j at j0=jt*4),      sg=t>>5 (4 samples s0b=sg*4)
//   L3 partials: t<128: jr=t>>5 (32-j chunk), sl=t&31 (sample)
//   L3 LIF:      t<160: o=t>>5, sl=t&31  (1 scalar m3/acc3 per thread)
//
// Weights: W2T read DIRECTLY from global each k (row k = 512 B shared by the
// whole block in lockstep -> L1-resident; no LDS staging, no extra barriers).
// Spikes: f32 {0,1} in LDS, col XOR-swizzle s^(4*((row>>4)&7)) keeps float2/
// float4 alignment, spreads phase-A store banks, reads are row-uniform.
// 3 barriers/step.
//
// LDS layout (bytes):
//   [0,36864)      s1F f32[256][36]
//   [36864,55296)  s2F f32[128][36]
//   [55296,59392)  W3L f32[128][8]
//   [59392,61952)  pL  f32[20][32]   ([o*4+jr][sample])
//   [61952,62484)  bL  f32[133]      (b2[128] ++ b3[5])
// Total 62592 -> 2 blocks/CU.
// ---------------------------------------------------------------------------
extern "C" __global__ void __launch_bounds__(256, 2) snn_main(
    const float* __restrict__ x,
    const float* __restrict__ b1,
    const float* __restrict__ b2g,
    const float* __restrict__ W3,
    const float* __restrict__ b3,
    const float* __restrict__ W1T,
    const float* __restrict__ W2T,
    float* __restrict__ out)
{
    __shared__ __align__(16) char ldsraw[62592];
    float* s1F = (float*)(ldsraw);            // [256][36]
    float* s2F = (float*)(ldsraw + 36864);    // [128][36]
    float* W3L = (float*)(ldsraw + 55296);    // [128][8]
    float* pL  = (float*)(ldsraw + 59392);    // [20][32]
    float* bL  = (float*)(ldsraw + 61952);    // [133]

    const int t   = threadIdx.x;
    const int nt  = t & 15;
    const int st  = t >> 4;
    const int s0a = st * 2;
    const int n0  = nt * 16;
    const int jt  = t & 31;
    const int sg  = t >> 5;
    const int s0b = sg * 4;
    const int sBase = blockIdx.x * 32;

    // ---- stage W3 (transposed, padded to 8) + biases ----
    for (int idx = t; idx < 640; idx += 256) {
        int o = idx >> 7;          // W3 is [5][128]
        int j = idx & 127;
        W3L[j * 8 + o] = W3[idx];
    }
    if (t < 128) bL[t] = b2g[t];
    if (t < 5)   bL[128 + t] = b3[t];

    // ---- cur1 = x @ W1.T, direct global reads (k ascending fmaf, bias after
    //      the dot — identical chain order to R2 => bit-exact) ----
    float cur1[16][2];
    #pragma unroll
    for (int i = 0; i < 16; ++i) { cur1[i][0] = 0.0f; cur1[i][1] = 0.0f; }

    const float* xr0 = x + (sBase + s0a) * 250;
    const float* xr1 = xr0 + 250;
    #pragma unroll 2
    for (int k = 0; k < 250; ++k) {
        const float x0 = xr0[k];
        const float x1 = xr1[k];
        float w[16];
        *(float4*)&w[0]  = *(const float4*)&W1T[k * 256 + n0];
        *(float4*)&w[4]  = *(const float4*)&W1T[k * 256 + n0 + 4];
        *(float4*)&w[8]  = *(const float4*)&W1T[k * 256 + n0 + 8];
        *(float4*)&w[12] = *(const float4*)&W1T[k * 256 + n0 + 12];
        #pragma unroll
        for (int i = 0; i < 16; ++i) {
            cur1[i][0] = fmaf(w[i], x0, cur1[i][0]);
            cur1[i][1] = fmaf(w[i], x1, cur1[i][1]);
        }
    }
    {
        float bb[16];
        *(float4*)&bb[0]  = *(const float4*)&b1[n0];
        *(float4*)&bb[4]  = *(const float4*)&b1[n0 + 4];
        *(float4*)&bb[8]  = *(const float4*)&b1[n0 + 8];
        *(float4*)&bb[12] = *(const float4*)&b1[n0 + 12];
        #pragma unroll
        for (int i = 0; i < 16; ++i) {
            cur1[i][0] = __fadd_rn(cur1[i][0], bb[i]);
            cur1[i][1] = __fadd_rn(cur1[i][1], bb[i]);
        }
    }

    __syncthreads();   // W3L/bL staged

    // ---- persistent state (fits 128 VGPR: 32+32+16+16+~20) ----
    float m1[16][2];
    #pragma unroll
    for (int i = 0; i < 16; ++i) { m1[i][0] = 0.0f; m1[i][1] = 0.0f; }
    float m2[4][4];
    #pragma unroll
    for (int jj = 0; jj < 4; ++jj)
        #pragma unroll
        for (int ss = 0; ss < 4; ++ss) m2[jj][ss] = 0.0f;
    float m3 = 0.0f, acc3 = 0.0f;

    const int keyA = (nt & 7) << 2;   // row-swizzle key for this thread's rows

    for (int stp = 0; stp < NSTEP; ++stp) {
        // ========== A: layer-1 LIF + f32 spikes -> LDS (swizzled) ==========
        #pragma unroll
        for (int i = 0; i < 16; ++i) {
            float2 pk;
            {
                float m = m1[i][0];
                float r = (m > 1.0f) ? 1.0f : 0.0f;
                m = __fsub_rn(__fadd_rn(__fmul_rn(0.9f, m), cur1[i][0]), r);
                m1[i][0] = m;
                pk.x = (m > 1.0f) ? 1.0f : 0.0f;
            }
            {
                float m = m1[i][1];
                float r = (m > 1.0f) ? 1.0f : 0.0f;
                m = __fsub_rn(__fadd_rn(__fmul_rn(0.9f, m), cur1[i][1]), r);
                m1[i][1] = m;
                pk.y = (m > 1.0f) ? 1.0f : 0.0f;
            }
            *(float2*)&s1F[(n0 + i) * 36 + (s0a ^ keyA)] = pk;
        }
        __syncthreads();   // bar1: s1 ready

        // ========== B: cur2 = s1 @ W2.T, W2T direct from global ==========
        float a2[4][4];
        #pragma unroll
        for (int jj = 0; jj < 4; ++jj)
            #pragma unroll
            for (int ss = 0; ss < 4; ++ss) a2[jj][ss] = 0.0f;

        #pragma unroll 4
        for (int k = 0; k < 256; ++k) {
            const float4 w  = *(const float4*)&W2T[k * 128 + jt * 4];
            const float4 sp = *(const float4*)&s1F[k * 36 + (s0b ^ (((k >> 4) & 7) << 2))];
            const float* wv = &w.x;
            const float* sv = &sp.x;
            #pragma unroll
            for (int jj = 0; jj < 4; ++jj)
                #pragma unroll
                for (int ss = 0; ss < 4; ++ss)
                    a2[jj][ss] = fmaf(wv[jj], sv[ss], a2[jj][ss]);
        }

        // ========== C: layer-2 LIF + f32 spikes -> LDS ==========
        #pragma unroll
        for (int jj = 0; jj < 4; ++jj) {
            const int j = jt * 4 + jj;
            const float bj = bL[j];
            float4 s2v;
            float* s2p = &s2v.x;
            #pragma unroll
            for (int ss = 0; ss < 4; ++ss) {
                float c2 = __fadd_rn(a2[jj][ss], bj);
                float m = m2[jj][ss];
                float r = (m > 1.0f) ? 1.0f : 0.0f;
                m = __fsub_rn(__fadd_rn(__fmul_rn(0.9f, m), c2), r);
                m2[jj][ss] = m;
                s2p[ss] = (m > 1.0f) ? 1.0f : 0.0f;
            }
            *(float4*)&s2F[j * 36 + s0b] = s2v;
        }
        __syncthreads();   // bar2: s2 ready

        // ========== D: layer-3 partial dots (4-way j split, as R2) ==========
        if (t < 128) {
            const int sl = t & 31;
            const int jr = t >> 5;
            float part[5] = {0.0f, 0.0f, 0.0f, 0.0f, 0.0f};
            #pragma unroll 8
            for (int jj = 0; jj < 32; ++jj) {
                const int j = jr * 32 + jj;
                const float s2v = s2F[j * 36 + sl];
                const float4 w3a = *(const float4*)&W3L[j * 8];
                const float  w3e = W3L[j * 8 + 4];
                part[0] = fmaf(w3a.x, s2v, part[0]);
                part[1] = fmaf(w3a.y, s2v, part[1]);
                part[2] = fmaf(w3a.z, s2v, part[2]);
                part[3] = fmaf(w3a.w, s2v, part[3]);
                part[4] = fmaf(w3e,   s2v, part[4]);
            }
            #pragma unroll
            for (int o = 0; o < 5; ++o)
                pL[(o * 4 + jr) * 32 + sl] = part[o];
        }
        __syncthreads();   // bar3: partials ready

        // ========== E: layer-3 LIF + spike count (1 (o,sample)/thread) ======
        if (t < 160) {
            const int o  = t >> 5;
            const int sl = t & 31;
            float c3 = pL[(o * 4 + 0) * 32 + sl];
            c3 += pL[(o * 4 + 1) * 32 + sl];
            c3 += pL[(o * 4 + 2) * 32 + sl];
            c3 += pL[(o * 4 + 3) * 32 + sl];
            c3 = __fadd_rn(c3, bL[128 + o]);
            float m = m3;
            float r = (m > 1.0f) ? 1.0f : 0.0f;
            m = __fsub_rn(__fadd_rn(__fmul_rn(0.9f, m), c3), r);
            m3 = m;
            if (m > 1.0f) acc3 += 1.0f;
        }
    }

    // ---- epilogue ----
    if (t < 160) {
        out[(sBase + (t & 31)) * 5 + (t >> 5)] = acc3;
    }
}

extern "C" void kernel_launch(void* const* d_in, const int* in_sizes, int n_in,
                              void* d_out, int out_size, void* d_ws, size_t ws_size,
                              hipStream_t stream) {
    const float* x  = (const float*)d_in[0];
    const float* W1 = (const float*)d_in[1];
    const float* b1 = (const float*)d_in[2];
    const float* W2 = (const float*)d_in[3];
    const float* b2 = (const float*)d_in[4];
    const float* W3 = (const float*)d_in[5];
    const float* b3 = (const float*)d_in[6];
    float* out = (float*)d_out;

    float* W1T = (float*)d_ws;            // 250*256 floats
    float* W2T = W1T + 250 * 256;         // 256*128 floats

    const int B = in_sizes[0] / 250;      // 131072
    const int nwg = B / 32;               // 4096

    snn_prep<<<128, 256, 0, stream>>>(W1, W2, W1T, W2T);
    snn_main<<<nwg, 256, 0, stream>>>(x, b1, b2, W3, b3, W1T, W2T, out);
}